// Round 15
// baseline (134.753 us; speedup 1.0000x reference)
//
#include <hip/hip_runtime.h>

typedef short short8 __attribute__((ext_vector_type(8)));
typedef short short4v __attribute__((ext_vector_type(4)));
typedef float f32x4 __attribute__((ext_vector_type(4)));
typedef float float4v __attribute__((ext_vector_type(4)));
typedef __bf16 bf16x8 __attribute__((ext_vector_type(8)));
typedef _Float16 half4 __attribute__((ext_vector_type(4)));
typedef _Float16 half2v __attribute__((ext_vector_type(2)));

__device__ __forceinline__ short f2bf(float x) {
  unsigned u = __builtin_bit_cast(unsigned, x);
  u += 0x7fffu + ((u >> 16) & 1u);   // round-to-nearest-even
  return (short)(u >> 16);
}

__device__ __forceinline__ f32x4 mfma16(short8 a, short8 b, f32x4 c) {
  return __builtin_amdgcn_mfma_f32_16x16x32_bf16(
      __builtin_bit_cast(bf16x8, a), __builtin_bit_cast(bf16x8, b), c, 0, 0, 0);
}

// async global->LDS, 16B per lane; lds is wave-uniform base (lane i writes base+i*16)
__device__ __forceinline__ void async16(void* lds, const void* g) {
  __builtin_amdgcn_global_load_lds(
      (const __attribute__((address_space(1))) unsigned*)g,
      (__attribute__((address_space(3))) unsigned*)lds, 16, 0, 0);
}

// ---------------- fused weight-transpose + CAPE + input cvt ----------------
// z=0..3: W transposes (Wq/Wk/Wv/Wo); z=4: hs f32->bf16 cvt.
__global__ __launch_bounds__(256) void capeT_all_kernel(
    const float* __restrict__ Wq, const float* __restrict__ Wk,
    const float* __restrict__ Wv, const float* __restrict__ Wo,
    const float* __restrict__ p_inv, const float* __restrict__ p_out,
    float qscale, short* __restrict__ BT0, short* __restrict__ BT1,
    short* __restrict__ wo_t, const float* __restrict__ hs,
    short* __restrict__ hs_bf) {
  const int ND = 1280, KD = 1280;
  const size_t SEC = (size_t)1280 * 1280;
  int z = blockIdx.z;
  int tx = threadIdx.x, ty = threadIdx.y;  // 32 x 8
  if (z == 4) {  // hs conversion
    int t = ty * 32 + tx;
    int base = ((blockIdx.y * 40 + blockIdx.x) * 256 + t) * 2;
    const int n4 = 2048 * 1280 / 4;
#pragma unroll
    for (int r = 0; r < 2; r++) {
      int i = base + r;
      if (i < n4) {
        float4v v = *(const float4v*)(hs + (size_t)i * 4);
        short4v o;
#pragma unroll
        for (int j = 0; j < 4; j++) o[j] = f2bf(v[j]);
        *(short4v*)(hs_bf + (size_t)i * 4) = o;
      }
    }
    return;
  }
  const float* W;
  const float* P;
  float scale = 1.0f;
  short *d0, *d1;
  if (z == 0) { W = Wq; P = p_inv; scale = qscale; d0 = BT0; d1 = BT1; }
  else if (z == 1) { W = Wk; P = p_out; d0 = BT0 + SEC; d1 = BT1 + SEC; }
  else if (z == 2) { W = Wv; P = nullptr; d0 = BT0 + 2 * SEC; d1 = BT1 + 2 * SEC; }
  else { W = Wo; P = nullptr; d0 = wo_t; d1 = nullptr; }

  __shared__ float tile[32][33];
  int bn = blockIdx.x * 32, bk = blockIdx.y * 32;
  for (int i = ty; i < 32; i += 8)
    tile[i][tx] = W[(size_t)(bk + i) * ND + bn + tx];
  __syncthreads();
  for (int c = ty; c < 32; c += 8) {
    float v0, v1;
    if (P) {
      int g = c & ~3, jj = c & 3;
      float a0 = 0.f, a1 = 0.f;
#pragma unroll
      for (int j = 0; j < 4; j++) {
        float wv = tile[tx][g + j];
        a0 += wv * P[j * 4 + jj];
        a1 += wv * P[16 + j * 4 + jj];
      }
      v0 = a0 * scale;
      v1 = a1 * scale;
    } else {
      v0 = v1 = tile[tx][c] * scale;
    }
    size_t o = (size_t)(bn + c) * KD + bk + tx;
    d0[o] = f2bf(v0);
    if (d1) d1[o] = f2bf(v1);
  }
}

// ---------------- GEMM 128x128 (QKV) with attention-layout epilogue --------
// XCD-swizzled grid (480 blocks, 480%8==0 -> bijective).
//   Q:  qb[h][s][64]
//   K:  ktl[h][kt][key][64] with 16B-chunk XOR swizzle
//   V:  vtl[h][kt][sub32][g=key>>2][dv^g][key&3] (bank-safe; half4 stores)

__global__ __launch_bounds__(256) void gemm128_qkv_kernel(
    const short* __restrict__ A, const short* __restrict__ B0,
    const short* __restrict__ B1, int M, int N, int K,
    short* __restrict__ qb, short* __restrict__ ktl,
    _Float16* __restrict__ vtl) {
  __shared__ __align__(16) short As[2][128][32];
  __shared__ __align__(16) short Bs[2][128][32];
  int tid = threadIdx.x;
  int l = tid & 63, w = tid >> 6;
  int wr = w >> 1, wc = w & 1;
  int lr = l & 15, lg = l >> 4;
  // XCD swizzle: same-XCD blocks take consecutive logical tiles (share A-panel)
  int nwg = gridDim.x * gridDim.y;
  int orig = blockIdx.y * gridDim.x + blockIdx.x;
  int wgid = (orig & 7) * (nwg >> 3) + (orig >> 3);
  int bxs = wgid % gridDim.x, bys = wgid / gridDim.x;
  int bm = bys * 128, bn = bxs * 128;
  const short* BT = (bm >= 1024) ? B1 : B0;
  f32x4 acc[4][4] = {};

  auto stage = [&](int b, int k0) {
    const short* ga = A + (size_t)(bm + (tid >> 2)) * K + k0 + (tid & 3) * 8;
    const short* gb = BT + (size_t)(bn + (tid >> 2)) * K + k0 + (tid & 3) * 8;
    char* la = (char*)&As[b][0][0] + w * 1024;
    char* lb = (char*)&Bs[b][0][0] + w * 1024;
    async16(la, ga);
    async16(la + 4096, ga + (size_t)64 * K);
    async16(lb, gb);
    async16(lb + 4096, gb + (size_t)64 * K);
  };

  auto compute = [&](int b) {
    const short* Ab = &As[b][0][0];
    const short* Bb = &Bs[b][0][0];
    short8 af[4], bf_[4];
#pragma unroll
    for (int mi = 0; mi < 4; mi++)
      af[mi] = *(const short8*)(Ab + (wr * 64 + mi * 16 + lr) * 32 + lg * 8);
#pragma unroll
    for (int nj = 0; nj < 4; nj++)
      bf_[nj] = *(const short8*)(Bb + (wc * 64 + nj * 16 + lr) * 32 + lg * 8);
#pragma unroll
    for (int mi = 0; mi < 4; mi++)
#pragma unroll
      for (int nj = 0; nj < 4; nj++)
        acc[mi][nj] = mfma16(af[mi], bf_[nj], acc[mi][nj]);
  };

  int nk = K >> 5;
  stage(0, 0);
  for (int ks = 0; ks < nk; ks += 2) {
    __syncthreads();
    if (ks + 1 < nk) stage(1, (ks + 1) << 5);
    compute(0);
    __syncthreads();
    if (ks + 2 < nk) stage(0, (ks + 2) << 5);
    compute(1);
  }

#pragma unroll
  for (int mi = 0; mi < 4; mi++)
#pragma unroll
    for (int nj = 0; nj < 4; nj++) {
      int s0 = bm + wr * 64 + mi * 16 + lg * 4;  // s0 % 4 == 0
      int col = bn + wc * 64 + nj * 16 + lr;
      if (col < 1280) {                       // Q rows
#pragma unroll
        for (int i = 0; i < 4; i++)
          qb[(((size_t)(col >> 6)) * 2048 + s0 + i) * 64 + (col & 63)] =
              f2bf(acc[mi][nj][i]);
      } else if (col < 2560) {                // K tiled + 16B-chunk swizzle
        int cc = col - 1280;
        int h = cc >> 6, d = cc & 63;
#pragma unroll
        for (int i = 0; i < 4; i++) {
          int s = s0 + i;
          int kt = s >> 6, r = s & 63;
          int kcol = (((d >> 3) ^ (r & 7)) << 3) | (d & 7);
          ktl[(((size_t)h * 32 + kt) * 64 + r) * 64 + kcol] = f2bf(acc[mi][nj][i]);
        }
      } else {                                // V: half4 store (4 consecutive keys)
        int cc = col - 2560;
        int h = cc >> 6, dv = cc & 63;
        int kt = s0 >> 6, key0 = s0 & 63;
        int sub = key0 >> 5, g = (key0 & 31) >> 2;
        half4 o;
#pragma unroll
        for (int i = 0; i < 4; i++) o[i] = (_Float16)acc[mi][nj][i];
        size_t vaddr = ((size_t)h * 32 + kt) * 4096 + sub * 2048 + g * 256 +
                       ((dv ^ g) << 2);
        *(half4*)(vtl + vaddr) = o;
      }
    }
}

// ---------------- GEMM 64x64 (output proj) with FUSED split-K combine -----
// A operand is built on the fly from attn partials:
//   A[s][c] = bf16( o0*s0(h,s) + o1*s1(h,s) ),  h = c>>6
// out = A @ wo_t^T + bias + resid.  XCD-swizzled grid (640 blocks).

__global__ __launch_bounds__(256) void gemm64_oc_kernel(
    const float* __restrict__ opart, const float2* __restrict__ ml,
    const short* __restrict__ BT, int M, int N, int K,
    const float* __restrict__ bias, const float* __restrict__ resid,
    float* __restrict__ out) {
  __shared__ __align__(16) short As[2][64][32];
  __shared__ __align__(16) short Bs[2][64][32];
  int tid = threadIdx.x;
  int l = tid & 63, w = tid >> 6;
  int wr = w >> 1, wc = w & 1;
  int lr = l & 15, lg = l >> 4;
  int nwg = gridDim.x * gridDim.y;
  int orig = blockIdx.y * gridDim.x + blockIdx.x;
  int wgid = (orig & 7) * (nwg >> 3) + (orig >> 3);
  int bxs = wgid % gridDim.x, bys = wgid / gridDim.x;
  int bm = bys * 64, bn = bxs * 64;
  f32x4 acc[2][2] = {};

  // per-thread A staging coordinates (row fixed, col varies with k0)
  int arow = bm + (tid >> 2);
  int aqb = arow >> 6, aql = arow & 63;

  auto stageA = [&](int b, int k0) {
    int c0 = k0 + (tid & 3) * 8;   // 8 consecutive cols, same head
    int h = c0 >> 6, dv0 = c0 & 63;
    size_t blk = (size_t)h * 32 + aqb;
    const float* o0 = opart + blk * 4096 + aql * 64 + dv0;
    const float* o1 = o0 + (size_t)640 * 4096;
    float2 m0 = ml[blk * 64 + aql];
    float2 m1 = ml[(size_t)640 * 64 + blk * 64 + aql];
    float Mx = fmaxf(m0.x, m1.x);
    float a0 = __builtin_amdgcn_exp2f(m0.x - Mx);
    float a1 = __builtin_amdgcn_exp2f(m1.x - Mx);
    float inv = 1.0f / (m0.y * a0 + m1.y * a1);
    float s0 = a0 * inv, s1 = a1 * inv;
    float4v v00 = *(const float4v*)(o0);
    float4v v01 = *(const float4v*)(o0 + 4);
    float4v v10 = *(const float4v*)(o1);
    float4v v11 = *(const float4v*)(o1 + 4);
    short8 r;
#pragma unroll
    for (int j = 0; j < 4; j++) {
      r[j] = f2bf(v00[j] * s0 + v10[j] * s1);
      r[4 + j] = f2bf(v01[j] * s0 + v11[j] * s1);
    }
    *(short8*)((char*)&As[b][0][0] + tid * 16) = r;
  };

  auto stageB = [&](int b, int k0) {
    const short* gb = BT + (size_t)(bn + (tid >> 2)) * K + k0 + (tid & 3) * 8;
    async16((char*)&Bs[b][0][0] + w * 1024, gb);
  };

  auto compute = [&](int b) {
    const short* Ab = &As[b][0][0];
    const short* Bb = &Bs[b][0][0];
    short8 af[2], bf_[2];
#pragma unroll
    for (int mi = 0; mi < 2; mi++)
      af[mi] = *(const short8*)(Ab + (wr * 32 + mi * 16 + lr) * 32 + lg * 8);
#pragma unroll
    for (int nj = 0; nj < 2; nj++)
      bf_[nj] = *(const short8*)(Bb + (wc * 32 + nj * 16 + lr) * 32 + lg * 8);
#pragma unroll
    for (int mi = 0; mi < 2; mi++)
#pragma unroll
      for (int nj = 0; nj < 2; nj++)
        acc[mi][nj] = mfma16(af[mi], bf_[nj], acc[mi][nj]);
  };

  int nk = K >> 5;
  stageB(0, 0);
  stageA(0, 0);
  for (int ks = 0; ks < nk; ks += 2) {
    __syncthreads();
    if (ks + 1 < nk) { stageB(1, (ks + 1) << 5); stageA(1, (ks + 1) << 5); }
    compute(0);
    __syncthreads();
    if (ks + 2 < nk) { stageB(0, (ks + 2) << 5); stageA(0, (ks + 2) << 5); }
    compute(1);
  }

#pragma unroll
  for (int mi = 0; mi < 2; mi++)
#pragma unroll
    for (int nj = 0; nj < 2; nj++)
#pragma unroll
      for (int i = 0; i < 4; i++) {
        int row = bm + wr * 32 + mi * 16 + lg * 4 + i;
        int col = bn + wc * 32 + nj * 16 + lr;
        out[(size_t)row * N + col] =
            acc[mi][nj][i] + bias[col] + resid[(size_t)row * N + col];
      }
}

// ---------------- KV-split flash attention, 32-key tiles (16KB LDS) --------
// Grid (20, 32, 2), XCD-swizzled so each XCD covers ~2.5 heads (K/V L2-resident).
// opart[half][h][qb][64q][64dv] f32, ml[half][h][qb][64q] = {m, lsum}.
__global__ __launch_bounds__(256) void attn_kernel(
    const short* __restrict__ qb, const short* __restrict__ k_tiled,
    const _Float16* __restrict__ v_tiled, float* __restrict__ opart,
    float2* __restrict__ ml) {
  const int S = 2048, HD = 64;
  // swizzle: logical index h-major so same-XCD blocks share a head's K/V
  int orig = (blockIdx.z * 32 + blockIdx.y) * 20 + blockIdx.x;  // 1280 blocks
  int wgid = (orig & 7) * 160 + (orig >> 3);
  int h = wgid / 64;
  int rem = wgid - h * 64;
  int qblk = rem & 31;
  int half = rem >> 5;
  int sbase = half * 32;  // 32-key subtile index base
  int tid = threadIdx.x;
  int w = tid >> 6, l = tid & 63;
  int lr = l & 15, lg = l >> 4;
  int q0 = qblk * 64 + w * 16;

  __shared__ __align__(16) short Kl[2][32][64];      // 4KB per buf
  __shared__ __align__(16) _Float16 Vl[2][2048];     // 4KB per buf

  const short* qptr = qb + ((size_t)h * S + q0 + lr) * HD;
  short8 qf0 = *(const short8*)(qptr + lg * 8);
  short8 qf1 = *(const short8*)(qptr + 32 + lg * 8);

  // stage one 32-key subtile: K 4KB + V 4KB, one async16 each per thread
  auto stageKV = [&](int b, int ts) {
    int kt = ts >> 1, sub = ts & 1;
    const short* gk = k_tiled + ((size_t)h * 32 + kt) * 4096 + sub * 2048 + tid * 8;
    const _Float16* gv = v_tiled + ((size_t)h * 32 + kt) * 4096 + sub * 2048 + tid * 8;
    async16((char*)&Kl[b][0][0] + w * 1024, gk);
    async16((char*)&Vl[b][0] + w * 1024, gv);
  };

  float m = -1e30f, lsum = 0.f;  // per-lane partial sum
  f32x4 oacc[4] = {};            // O[q=lg*4+i][dv=nb*16+lr]

  auto compute_tile = [&](int buf) {
    const short* Kb = &Kl[buf][0][0];
    const _Float16* Vb = &Vl[buf][0];
    f32x4 st[2];
    __builtin_amdgcn_s_setprio(1);
#pragma unroll
    for (int kk = 0; kk < 2; kk++) {
      int r = kk * 16 + lr;
      int sw = r & 7;
      short8 kf0 = *(const short8*)(Kb + r * 64 + ((lg ^ sw) << 3));
      short8 kf1 = *(const short8*)(Kb + r * 64 + (((4 + lg) ^ sw) << 3));
      f32x4 s0 = {};
      s0 = mfma16(kf0, qf0, s0);
      s0 = mfma16(kf1, qf1, s0);
      st[kk] = s0;
    }
    __builtin_amdgcn_s_setprio(0);
    float m0 = fmaxf(fmaxf(st[0][0], st[0][1]), fmaxf(st[0][2], st[0][3]));
    float m1 = fmaxf(fmaxf(st[1][0], st[1][1]), fmaxf(st[1][2], st[1][3]));
    float pmax = fmaxf(m0, m1);
    if (!__all(pmax <= m + 8.0f)) {  // defer-rescale (T13); rare path
      float tm = pmax;
      tm = fmaxf(tm, __shfl_xor(tm, 16));
      tm = fmaxf(tm, __shfl_xor(tm, 32));
      float mnew = fmaxf(m, tm);
      float fac = __builtin_amdgcn_exp2f(m - mnew);
      lsum *= fac;
#pragma unroll
      for (int i = 0; i < 4; i++) {
        float fi = __shfl(fac, lg * 4 + i);
#pragma unroll
        for (int nb = 0; nb < 4; nb++) oacc[nb][i] *= fi;
      }
      m = mnew;
    }
    half4 pf[2];
    float ps[2];
#pragma unroll
    for (int kk = 0; kk < 2; kk++) {
      float p0 = __builtin_amdgcn_exp2f(st[kk][0] - m);
      float p1 = __builtin_amdgcn_exp2f(st[kk][1] - m);
      float p2 = __builtin_amdgcn_exp2f(st[kk][2] - m);
      float p3 = __builtin_amdgcn_exp2f(st[kk][3] - m);
      half2v lo = __builtin_bit_cast(half2v, __builtin_amdgcn_cvt_pkrtz(p0, p1));
      half2v hi = __builtin_bit_cast(half2v, __builtin_amdgcn_cvt_pkrtz(p2, p3));
      pf[kk][0] = lo[0]; pf[kk][1] = lo[1];
      pf[kk][2] = hi[0]; pf[kk][3] = hi[1];
      ps[kk] = (p0 + p1) + (p2 + p3);
    }
    lsum += ps[0] + ps[1];
#pragma unroll
    for (int kk = 0; kk < 2; kk++) {
      half4 vf[4];
#pragma unroll
      for (int nb = 0; nb < 4; nb++) {
        int dv = nb * 16 + lr;
        int g = (kk << 2) + lg;
        vf[nb] = *(const half4*)(Vb + (g << 8) + ((dv ^ g) << 2));
      }
      __builtin_amdgcn_s_setprio(1);
#pragma unroll
      for (int nb = 0; nb < 4; nb++)
        oacc[nb] = __builtin_amdgcn_mfma_f32_16x16x16f16(pf[kk], vf[nb], oacc[nb], 0, 0, 0);
      __builtin_amdgcn_s_setprio(0);
    }
  };

  stageKV(0, sbase);
  for (int t2 = 0; t2 < 32; t2 += 2) {
    __syncthreads();
    if (t2 + 1 < 32) stageKV(1, sbase + t2 + 1);
    compute_tile(0);
    __syncthreads();
    if (t2 + 2 < 32) stageKV(0, sbase + t2 + 2);
    compute_tile(1);
  }

  // finalize partials
  lsum += __shfl_xor(lsum, 16);
  lsum += __shfl_xor(lsum, 32);

  size_t blk = (size_t)half * 640 + h * 32 + qblk;
  float* obase = opart + blk * 4096;
#pragma unroll
  for (int i = 0; i < 4; i++) {
    int ql = w * 16 + lg * 4 + i;
#pragma unroll
    for (int nb = 0; nb < 4; nb++)
      obase[ql * 64 + nb * 16 + lr] = oacc[nb][i];
  }
  if (lg == 0) {  // lanes 0..15 hold (m, lsum) for q-row lr
    float2 v;
    v.x = m;
    v.y = lsum;
    ml[blk * 64 + w * 16 + lr] = v;
  }
}

// ---------------- launch ----------------

extern "C" void kernel_launch(void* const* d_in, const int* in_sizes, int n_in,
                              void* d_out, int out_size, void* d_ws, size_t ws_size,
                              hipStream_t stream) {
  const float* hs = (const float*)d_in[0];
  const float* p_out = (const float*)d_in[1];
  const float* p_inv = (const float*)d_in[2];
  const float* Wq = (const float*)d_in[3];
  const float* Wk = (const float*)d_in[4];
  const float* Wv = (const float*)d_in[5];
  const float* Wo = (const float*)d_in[6];
  const float* bo = (const float*)d_in[7];
  float* out = (float*)d_out;
  char* ws = (char*)d_ws;

  // workspace layout (bytes)
  short* hs_bf = (short*)(ws + 0);                  //  5,242,880
  short* BT0 = (short*)(ws + 5242880);              //  9,830,400
  short* BT1 = (short*)(ws + 15073280);             //  9,830,400
  short* wo_t = (short*)(ws + 24903680);            //  3,276,800
  short* q_bf = (short*)(ws + 28180480);            //  5,242,880
  short* k_tiled = (short*)(ws + 33423360);         //  5,242,880
  _Float16* v_tiled = (_Float16*)(ws + 38666240);   //  5,242,880 (ends 43,909,120)
  // attn partials overlay hs_bf/BT0/BT1 (dead after QKV GEMM); wo_t survives:
  float* opart = (float*)(ws + 0);                  // 20,971,520
  float2* ml = (float2*)(ws + 22020096);            //    655,360 (< 24,903,680)

  const float QSCALE = 0.125f * 1.44269504f;  // hd^-0.5 * log2(e)

  capeT_all_kernel<<<dim3(40, 40, 5), dim3(32, 8), 0, stream>>>(
      Wq, Wk, Wv, Wo, p_inv, p_out, QSCALE, BT0, BT1, wo_t, hs, hs_bf);

  gemm128_qkv_kernel<<<dim3(30, 16), 256, 0, stream>>>(
      hs_bf, BT0, BT1, 2048, 3840, 1280, q_bf, k_tiled, v_tiled);

  attn_kernel<<<dim3(20, 32, 2), 256, 0, stream>>>(
      q_bf, k_tiled, v_tiled, opart, ml);

  // output projection with fused split-K combine (reads partials directly)
  gemm64_oc_kernel<<<dim3(20, 32), 256, 0, stream>>>(
      opart, ml, wo_t, 2048, 1280, 1280, bo, hs, out);
}

// Round 16
// 115.037 us; speedup vs baseline: 1.1714x; 1.1714x over previous
//
#include <hip/hip_runtime.h>

typedef short short8 __attribute__((ext_vector_type(8)));
typedef short short4v __attribute__((ext_vector_type(4)));
typedef float f32x4 __attribute__((ext_vector_type(4)));
typedef float float4v __attribute__((ext_vector_type(4)));
typedef __bf16 bf16x8 __attribute__((ext_vector_type(8)));
typedef _Float16 half4 __attribute__((ext_vector_type(4)));
typedef _Float16 half8 __attribute__((ext_vector_type(8)));
typedef _Float16 half2v __attribute__((ext_vector_type(2)));

__device__ __forceinline__ short f2bf(float x) {
  unsigned u = __builtin_bit_cast(unsigned, x);
  u += 0x7fffu + ((u >> 16) & 1u);   // round-to-nearest-even
  return (short)(u >> 16);
}

__device__ __forceinline__ f32x4 mfma16(short8 a, short8 b, f32x4 c) {
  return __builtin_amdgcn_mfma_f32_16x16x32_bf16(
      __builtin_bit_cast(bf16x8, a), __builtin_bit_cast(bf16x8, b), c, 0, 0, 0);
}

// async global->LDS, 16B per lane; lds is wave-uniform base (lane i writes base+i*16)
__device__ __forceinline__ void async16(void* lds, const void* g) {
  __builtin_amdgcn_global_load_lds(
      (const __attribute__((address_space(1))) unsigned*)g,
      (__attribute__((address_space(3))) unsigned*)lds, 16, 0, 0);
}

// ---------------- fused weight-transpose + CAPE + input cvt ----------------
// z=0..3: W transposes (Wq/Wk/Wv/Wo); z=4: hs f32->bf16 cvt.
// V (z==2) written once (no CAPE-t dependence).
__global__ __launch_bounds__(256) void capeT_all_kernel(
    const float* __restrict__ Wq, const float* __restrict__ Wk,
    const float* __restrict__ Wv, const float* __restrict__ Wo,
    const float* __restrict__ p_inv, const float* __restrict__ p_out,
    float qscale, short* __restrict__ BT0, short* __restrict__ BT1,
    short* __restrict__ wo_t, const float* __restrict__ hs,
    short* __restrict__ hs_bf) {
  const int ND = 1280, KD = 1280;
  const size_t SEC = (size_t)1280 * 1280;
  int z = blockIdx.z;
  int tx = threadIdx.x, ty = threadIdx.y;  // 32 x 8
  if (z == 4) {  // hs conversion
    int t = ty * 32 + tx;
    int base = ((blockIdx.y * 40 + blockIdx.x) * 256 + t) * 2;
    const int n4 = 2048 * 1280 / 4;
#pragma unroll
    for (int r = 0; r < 2; r++) {
      int i = base + r;
      if (i < n4) {
        float4v v = *(const float4v*)(hs + (size_t)i * 4);
        short4v o;
#pragma unroll
        for (int j = 0; j < 4; j++) o[j] = f2bf(v[j]);
        *(short4v*)(hs_bf + (size_t)i * 4) = o;
      }
    }
    return;
  }
  const float* W;
  const float* P;
  float scale = 1.0f;
  short *d0, *d1;
  if (z == 0) { W = Wq; P = p_inv; scale = qscale; d0 = BT0; d1 = BT1; }
  else if (z == 1) { W = Wk; P = p_out; d0 = BT0 + SEC; d1 = BT1 + SEC; }
  else if (z == 2) { W = Wv; P = nullptr; d0 = BT0 + 2 * SEC; d1 = nullptr; }
  else { W = Wo; P = nullptr; d0 = wo_t; d1 = nullptr; }

  __shared__ float tile[32][33];
  int bn = blockIdx.x * 32, bk = blockIdx.y * 32;
  for (int i = ty; i < 32; i += 8)
    tile[i][tx] = W[(size_t)(bk + i) * ND + bn + tx];
  __syncthreads();
  for (int c = ty; c < 32; c += 8) {
    float v0, v1;
    if (P) {
      int g = c & ~3, jj = c & 3;
      float a0 = 0.f, a1 = 0.f;
#pragma unroll
      for (int j = 0; j < 4; j++) {
        float wv = tile[tx][g + j];
        a0 += wv * P[j * 4 + jj];
        a1 += wv * P[16 + j * 4 + jj];
      }
      v0 = a0 * scale;
      v1 = a1 * scale;
    } else {
      v0 = v1 = tile[tx][c] * scale;
    }
    size_t o = (size_t)(bn + c) * KD + bk + tx;
    d0[o] = f2bf(v0);
    if (d1) d1[o] = f2bf(v1);
  }
}

// ---------------- GEMM 128x128 (QKV) with attention-layout epilogue --------
// XCD-swizzled grid (480 blocks, 480%8==0 -> bijective).
//   Q:  qb[h][s][64]
//   K:  ktl[h][kt][key][64] with 16B-chunk XOR swizzle
//   V:  vtl[h][kt][sub32][g=key>>2][dv^g][key&3] (bank-safe; half4 stores)
// V weight section has no t-dependence -> B0 for bn>=2560.

__global__ __launch_bounds__(256) void gemm128_qkv_kernel(
    const short* __restrict__ A, const short* __restrict__ B0,
    const short* __restrict__ B1, int M, int N, int K,
    short* __restrict__ qb, short* __restrict__ ktl,
    _Float16* __restrict__ vtl) {
  __shared__ __align__(16) short As[2][128][32];
  __shared__ __align__(16) short Bs[2][128][32];
  int tid = threadIdx.x;
  int l = tid & 63, w = tid >> 6;
  int wr = w >> 1, wc = w & 1;
  int lr = l & 15, lg = l >> 4;
  // XCD swizzle: same-XCD blocks take consecutive logical tiles (share A-panel)
  int nwg = gridDim.x * gridDim.y;
  int orig = blockIdx.y * gridDim.x + blockIdx.x;
  int wgid = (orig & 7) * (nwg >> 3) + (orig >> 3);
  int bxs = wgid % gridDim.x, bys = wgid / gridDim.x;
  int bm = bys * 128, bn = bxs * 128;
  const short* BT = (bn >= 2560) ? B0 : ((bm >= 1024) ? B1 : B0);
  f32x4 acc[4][4] = {};

  auto stage = [&](int b, int k0) {
    const short* ga = A + (size_t)(bm + (tid >> 2)) * K + k0 + (tid & 3) * 8;
    const short* gb = BT + (size_t)(bn + (tid >> 2)) * K + k0 + (tid & 3) * 8;
    char* la = (char*)&As[b][0][0] + w * 1024;
    char* lb = (char*)&Bs[b][0][0] + w * 1024;
    async16(la, ga);
    async16(la + 4096, ga + (size_t)64 * K);
    async16(lb, gb);
    async16(lb + 4096, gb + (size_t)64 * K);
  };

  auto compute = [&](int b) {
    const short* Ab = &As[b][0][0];
    const short* Bb = &Bs[b][0][0];
    short8 af[4], bf_[4];
#pragma unroll
    for (int mi = 0; mi < 4; mi++)
      af[mi] = *(const short8*)(Ab + (wr * 64 + mi * 16 + lr) * 32 + lg * 8);
#pragma unroll
    for (int nj = 0; nj < 4; nj++)
      bf_[nj] = *(const short8*)(Bb + (wc * 64 + nj * 16 + lr) * 32 + lg * 8);
#pragma unroll
    for (int mi = 0; mi < 4; mi++)
#pragma unroll
      for (int nj = 0; nj < 4; nj++)
        acc[mi][nj] = mfma16(af[mi], bf_[nj], acc[mi][nj]);
  };

  int nk = K >> 5;
  stage(0, 0);
  for (int ks = 0; ks < nk; ks += 2) {
    __syncthreads();
    if (ks + 1 < nk) stage(1, (ks + 1) << 5);
    compute(0);
    __syncthreads();
    if (ks + 2 < nk) stage(0, (ks + 2) << 5);
    compute(1);
  }

#pragma unroll
  for (int mi = 0; mi < 4; mi++)
#pragma unroll
    for (int nj = 0; nj < 4; nj++) {
      int s0 = bm + wr * 64 + mi * 16 + lg * 4;  // s0 % 4 == 0
      int col = bn + wc * 64 + nj * 16 + lr;
      if (col < 1280) {                       // Q rows
#pragma unroll
        for (int i = 0; i < 4; i++)
          qb[(((size_t)(col >> 6)) * 2048 + s0 + i) * 64 + (col & 63)] =
              f2bf(acc[mi][nj][i]);
      } else if (col < 2560) {                // K tiled + 16B-chunk swizzle
        int cc = col - 1280;
        int h = cc >> 6, d = cc & 63;
#pragma unroll
        for (int i = 0; i < 4; i++) {
          int s = s0 + i;
          int kt = s >> 6, r = s & 63;
          int kcol = (((d >> 3) ^ (r & 7)) << 3) | (d & 7);
          ktl[(((size_t)h * 32 + kt) * 64 + r) * 64 + kcol] = f2bf(acc[mi][nj][i]);
        }
      } else {                                // V: half4 store (4 consecutive keys)
        int cc = col - 2560;
        int h = cc >> 6, dv = cc & 63;
        int kt = s0 >> 6, key0 = s0 & 63;
        int sub = key0 >> 5, g = (key0 & 31) >> 2;
        half4 o;
#pragma unroll
        for (int i = 0; i < 4; i++) o[i] = (_Float16)acc[mi][nj][i];
        size_t vaddr = ((size_t)h * 32 + kt) * 4096 + sub * 2048 + g * 256 +
                       ((dv ^ g) << 2);
        *(half4*)(vtl + vaddr) = o;
      }
    }
}

// ---------------- GEMM 64x64 (output proj): out = A@BT^T + bias + resid ----
// XCD-swizzled grid (640 blocks, 640%8==0 -> bijective).

__global__ __launch_bounds__(256) void gemm64_o_kernel(
    const short* __restrict__ A, const short* __restrict__ BT,
    int M, int N, int K, const float* __restrict__ bias,
    const float* __restrict__ resid, float* __restrict__ out) {
  __shared__ __align__(16) short As[2][64][32];
  __shared__ __align__(16) short Bs[2][64][32];
  int tid = threadIdx.x;
  int l = tid & 63, w = tid >> 6;
  int wr = w >> 1, wc = w & 1;
  int lr = l & 15, lg = l >> 4;
  int nwg = gridDim.x * gridDim.y;
  int orig = blockIdx.y * gridDim.x + blockIdx.x;
  int wgid = (orig & 7) * (nwg >> 3) + (orig >> 3);
  int bxs = wgid % gridDim.x, bys = wgid / gridDim.x;
  int bm = bys * 64, bn = bxs * 64;
  f32x4 acc[2][2] = {};

  auto stage = [&](int b, int k0) {
    const short* ga = A + (size_t)(bm + (tid >> 2)) * K + k0 + (tid & 3) * 8;
    const short* gb = BT + (size_t)(bn + (tid >> 2)) * K + k0 + (tid & 3) * 8;
    async16((char*)&As[b][0][0] + w * 1024, ga);
    async16((char*)&Bs[b][0][0] + w * 1024, gb);
  };

  auto compute = [&](int b) {
    const short* Ab = &As[b][0][0];
    const short* Bb = &Bs[b][0][0];
    short8 af[2], bf_[2];
#pragma unroll
    for (int mi = 0; mi < 2; mi++)
      af[mi] = *(const short8*)(Ab + (wr * 32 + mi * 16 + lr) * 32 + lg * 8);
#pragma unroll
    for (int nj = 0; nj < 2; nj++)
      bf_[nj] = *(const short8*)(Bb + (wc * 32 + nj * 16 + lr) * 32 + lg * 8);
#pragma unroll
    for (int mi = 0; mi < 2; mi++)
#pragma unroll
      for (int nj = 0; nj < 2; nj++)
        acc[mi][nj] = mfma16(af[mi], bf_[nj], acc[mi][nj]);
  };

  int nk = K >> 5;
  stage(0, 0);
  for (int ks = 0; ks < nk; ks += 2) {
    __syncthreads();
    if (ks + 1 < nk) stage(1, (ks + 1) << 5);
    compute(0);
    __syncthreads();
    if (ks + 2 < nk) stage(0, (ks + 2) << 5);
    compute(1);
  }

#pragma unroll
  for (int mi = 0; mi < 2; mi++)
#pragma unroll
    for (int nj = 0; nj < 2; nj++)
#pragma unroll
      for (int i = 0; i < 4; i++) {
        int row = bm + wr * 32 + mi * 16 + lg * 4 + i;
        int col = bn + wc * 32 + nj * 16 + lr;
        out[(size_t)row * N + col] =
            acc[mi][nj][i] + bias[col] + resid[(size_t)row * N + col];
      }
}

// ---------------- KV-split flash attention, 32-key tiles (16KB LDS) --------
// Grid (20, 32, 2), XCD-swizzled so each XCD covers ~2.5 heads (K/V L2-resident).
// opart (f16) [half][h][qb][64q][64dv], ml[half][h][qb][64q] = {m, lsum}.
__global__ __launch_bounds__(256) void attn_kernel(
    const short* __restrict__ qb, const short* __restrict__ k_tiled,
    const _Float16* __restrict__ v_tiled, _Float16* __restrict__ opart,
    float2* __restrict__ ml) {
  const int S = 2048, HD = 64;
  // swizzle: logical index h-major so same-XCD blocks share a head's K/V
  int orig = (blockIdx.z * 32 + blockIdx.y) * 20 + blockIdx.x;  // 1280 blocks
  int wgid = (orig & 7) * 160 + (orig >> 3);
  int h = wgid / 64;
  int rem = wgid - h * 64;
  int qblk = rem & 31;
  int half = rem >> 5;
  int sbase = half * 32;  // 32-key subtile index base
  int tid = threadIdx.x;
  int w = tid >> 6, l = tid & 63;
  int lr = l & 15, lg = l >> 4;
  int q0 = qblk * 64 + w * 16;

  __shared__ __align__(16) short Kl[2][32][64];      // 4KB per buf
  __shared__ __align__(16) _Float16 Vl[2][2048];     // 4KB per buf

  const short* qptr = qb + ((size_t)h * S + q0 + lr) * HD;
  short8 qf0 = *(const short8*)(qptr + lg * 8);
  short8 qf1 = *(const short8*)(qptr + 32 + lg * 8);

  // stage one 32-key subtile: K 4KB + V 4KB, one async16 each per thread
  auto stageKV = [&](int b, int ts) {
    int kt = ts >> 1, sub = ts & 1;
    const short* gk = k_tiled + ((size_t)h * 32 + kt) * 4096 + sub * 2048 + tid * 8;
    const _Float16* gv = v_tiled + ((size_t)h * 32 + kt) * 4096 + sub * 2048 + tid * 8;
    async16((char*)&Kl[b][0][0] + w * 1024, gk);
    async16((char*)&Vl[b][0] + w * 1024, gv);
  };

  float m = -1e30f, lsum = 0.f;  // per-lane partial sum
  f32x4 oacc[4] = {};            // O[q=lg*4+i][dv=nb*16+lr]

  auto compute_tile = [&](int buf) {
    const short* Kb = &Kl[buf][0][0];
    const _Float16* Vb = &Vl[buf][0];
    f32x4 st[2];
    __builtin_amdgcn_s_setprio(1);
#pragma unroll
    for (int kk = 0; kk < 2; kk++) {
      int r = kk * 16 + lr;
      int sw = r & 7;
      short8 kf0 = *(const short8*)(Kb + r * 64 + ((lg ^ sw) << 3));
      short8 kf1 = *(const short8*)(Kb + r * 64 + (((4 + lg) ^ sw) << 3));
      f32x4 s0 = {};
      s0 = mfma16(kf0, qf0, s0);
      s0 = mfma16(kf1, qf1, s0);
      st[kk] = s0;
    }
    __builtin_amdgcn_s_setprio(0);
    float m0 = fmaxf(fmaxf(st[0][0], st[0][1]), fmaxf(st[0][2], st[0][3]));
    float m1 = fmaxf(fmaxf(st[1][0], st[1][1]), fmaxf(st[1][2], st[1][3]));
    float pmax = fmaxf(m0, m1);
    if (!__all(pmax <= m + 8.0f)) {  // defer-rescale (T13); rare path
      float tm = pmax;
      tm = fmaxf(tm, __shfl_xor(tm, 16));
      tm = fmaxf(tm, __shfl_xor(tm, 32));
      float mnew = fmaxf(m, tm);
      float fac = __builtin_amdgcn_exp2f(m - mnew);
      lsum *= fac;
#pragma unroll
      for (int i = 0; i < 4; i++) {
        float fi = __shfl(fac, lg * 4 + i);
#pragma unroll
        for (int nb = 0; nb < 4; nb++) oacc[nb][i] *= fi;
      }
      m = mnew;
    }
    half4 pf[2];
    float ps[2];
#pragma unroll
    for (int kk = 0; kk < 2; kk++) {
      float p0 = __builtin_amdgcn_exp2f(st[kk][0] - m);
      float p1 = __builtin_amdgcn_exp2f(st[kk][1] - m);
      float p2 = __builtin_amdgcn_exp2f(st[kk][2] - m);
      float p3 = __builtin_amdgcn_exp2f(st[kk][3] - m);
      half2v lo = __builtin_bit_cast(half2v, __builtin_amdgcn_cvt_pkrtz(p0, p1));
      half2v hi = __builtin_bit_cast(half2v, __builtin_amdgcn_cvt_pkrtz(p2, p3));
      pf[kk][0] = lo[0]; pf[kk][1] = lo[1];
      pf[kk][2] = hi[0]; pf[kk][3] = hi[1];
      ps[kk] = (p0 + p1) + (p2 + p3);
    }
    lsum += ps[0] + ps[1];
#pragma unroll
    for (int kk = 0; kk < 2; kk++) {
      half4 vf[4];
#pragma unroll
      for (int nb = 0; nb < 4; nb++) {
        int dv = nb * 16 + lr;
        int g = (kk << 2) + lg;
        vf[nb] = *(const half4*)(Vb + (g << 8) + ((dv ^ g) << 2));
      }
      __builtin_amdgcn_s_setprio(1);
#pragma unroll
      for (int nb = 0; nb < 4; nb++)
        oacc[nb] = __builtin_amdgcn_mfma_f32_16x16x16f16(pf[kk], vf[nb], oacc[nb], 0, 0, 0);
      __builtin_amdgcn_s_setprio(0);
    }
  };

  stageKV(0, sbase);
  for (int t2 = 0; t2 < 32; t2 += 2) {
    __syncthreads();
    if (t2 + 1 < 32) stageKV(1, sbase + t2 + 1);
    compute_tile(0);
    __syncthreads();
    if (t2 + 2 < 32) stageKV(0, sbase + t2 + 2);
    compute_tile(1);
  }

  // finalize partials
  lsum += __shfl_xor(lsum, 16);
  lsum += __shfl_xor(lsum, 32);

  size_t blk = (size_t)half * 640 + h * 32 + qblk;
  _Float16* obase = opart + blk * 4096;
#pragma unroll
  for (int i = 0; i < 4; i++) {
    int ql = w * 16 + lg * 4 + i;
#pragma unroll
    for (int nb = 0; nb < 4; nb++)
      obase[ql * 64 + nb * 16 + lr] = (_Float16)oacc[nb][i];
  }
  if (lg == 0) {  // lanes 0..15 hold (m, lsum) for q-row lr
    float2 v;
    v.x = m;
    v.y = lsum;
    ml[blk * 64 + w * 16 + lr] = v;
  }
}

// ---------------- split-K combine: 2 halves -> normalized bf16 attn_out ----
__global__ __launch_bounds__(256) void attn_combine_kernel(
    const _Float16* __restrict__ opart, const float2* __restrict__ ml,
    short* __restrict__ attn_out) {
  int h = blockIdx.x, qb = blockIdx.y;
  int t = threadIdx.x;
  int ql = t >> 2, dq = (t & 3) * 16;
  size_t blk = (size_t)h * 32 + qb;
  float2 ml0 = ml[blk * 64 + ql];
  float2 ml1 = ml[(size_t)640 * 64 + blk * 64 + ql];
  float M = fmaxf(ml0.x, ml1.x);
  float a0 = __builtin_amdgcn_exp2f(ml0.x - M);
  float a1 = __builtin_amdgcn_exp2f(ml1.x - M);
  float inv = 1.0f / (ml0.y * a0 + ml1.y * a1);
  float s0 = a0 * inv, s1 = a1 * inv;
  const _Float16* o0 = opart + blk * 4096 + ql * 64 + dq;
  const _Float16* o1 = o0 + (size_t)640 * 4096;
  int row = qb * 64 + ql;
  short* dst = attn_out + (size_t)row * 1280 + h * 64 + dq;
#pragma unroll
  for (int d = 0; d < 16; d += 8) {
    half8 v0 = *(const half8*)(o0 + d);
    half8 v1 = *(const half8*)(o1 + d);
    short8 o;
#pragma unroll
    for (int j = 0; j < 8; j++)
      o[j] = f2bf((float)v0[j] * s0 + (float)v1[j] * s1);
    *(short8*)(dst + d) = o;
  }
}

// ---------------- launch ----------------

extern "C" void kernel_launch(void* const* d_in, const int* in_sizes, int n_in,
                              void* d_out, int out_size, void* d_ws, size_t ws_size,
                              hipStream_t stream) {
  const float* hs = (const float*)d_in[0];
  const float* p_out = (const float*)d_in[1];
  const float* p_inv = (const float*)d_in[2];
  const float* Wq = (const float*)d_in[3];
  const float* Wk = (const float*)d_in[4];
  const float* Wv = (const float*)d_in[5];
  const float* Wo = (const float*)d_in[6];
  const float* bo = (const float*)d_in[7];
  float* out = (float*)d_out;
  char* ws = (char*)d_ws;

  // workspace layout (bytes)
  short* hs_bf = (short*)(ws + 0);                  //  5,242,880
  short* BT0 = (short*)(ws + 5242880);              //  9,830,400
  short* BT1 = (short*)(ws + 15073280);             //  9,830,400
  short* wo_t = (short*)(ws + 24903680);            //  3,276,800
  short* q_bf = (short*)(ws + 28180480);            //  5,242,880
  short* k_tiled = (short*)(ws + 33423360);         //  5,242,880
  _Float16* v_tiled = (_Float16*)(ws + 38666240);   //  5,242,880
  short* attn_bf = (short*)(ws + 43909120);         //  5,242,880 (ends 49,152,000)
  // attn partials (f16) overlay hs_bf/BT0 (dead after QKV GEMM); wo_t survives:
  _Float16* opart = (_Float16*)(ws + 0);            // 10,485,760
  float2* ml = (float2*)(ws + 22020096);            //    655,360 (< 24,903,680)

  const float QSCALE = 0.125f * 1.44269504f;  // hd^-0.5 * log2(e)

  capeT_all_kernel<<<dim3(40, 40, 5), dim3(32, 8), 0, stream>>>(
      Wq, Wk, Wv, Wo, p_inv, p_out, QSCALE, BT0, BT1, wo_t, hs, hs_bf);

  gemm128_qkv_kernel<<<dim3(30, 16), 256, 0, stream>>>(
      hs_bf, BT0, BT1, 2048, 3840, 1280, q_bf, k_tiled, v_tiled);

  attn_kernel<<<dim3(20, 32, 2), 256, 0, stream>>>(
      q_bf, k_tiled, v_tiled, opart, ml);

  attn_combine_kernel<<<dim3(20, 32), 256, 0, stream>>>(opart, ml, attn_bf);

  gemm64_o_kernel<<<dim3(20, 32), 256, 0, stream>>>(
      attn_bf, wo_t, 2048, 1280, 1280, bo, hs, out);
}